// Round 7
// baseline (224.620 us; speedup 1.0000x reference)
//
#include <hip/hip_runtime.h>
#include <hip/hip_bf16.h>
#include <math.h>

typedef __bf16 bf16;
typedef __attribute__((ext_vector_type(8))) __bf16 bf16x8;
typedef __attribute__((ext_vector_type(4))) __bf16 bf16x4;
typedef __attribute__((ext_vector_type(4))) float f32x4;

#define MFMA16(a, b, c) __builtin_amdgcn_mfma_f32_16x16x32_bf16((a), (b), (c), 0, 0, 0)

// XOR swizzle for [rows][64] bf16 LDS tiles (128 B row = 32 banks exactly).
__device__ __forceinline__ int swz(int row, int col) {
  return row * 64 + ((((col) >> 3) ^ (row & 7)) << 3) + (col & 7);
}

// async global->LDS, 16B per lane. LDS dest is wave-uniform base + lane*16.
__device__ __forceinline__ void gl_lds16(const bf16* g, bf16* l) {
  __builtin_amdgcn_global_load_lds(
      (const __attribute__((address_space(1))) void*)g,
      (__attribute__((address_space(3))) void*)l, 16, 0, 0);
}

// ---------------------------------------------------------------------------
// f32 -> bf16 cast, 4 elems/thread
// ---------------------------------------------------------------------------
__global__ __launch_bounds__(256) void cvt_f32_bf16(const float* __restrict__ in,
                                                    bf16* __restrict__ out, int n4) {
  int i = blockIdx.x * 256 + threadIdx.x;
  if (i < n4) {
    float4 v = ((const float4*)in)[i];
    bf16x4 o = {(bf16)v.x, (bf16)v.y, (bf16)v.z, (bf16)v.w};
    ((bf16x4*)out)[i] = o;
  }
}

// ---------------------------------------------------------------------------
// GEMM, C[m,n] = sum_k A[m,k]*B[n,k]  (both row-major, "B^T" layout)
// BM=BN=128, BK=64, 256 threads = 4 waves in 2x2, each wave 64x64 out.
// Staging via global_load_lds (linear LDS dest, pre-swizzled global src);
// reads use XOR swizzle -> conflict-free both sides.
// ---------------------------------------------------------------------------
__global__ __launch_bounds__(256) void gemm_bt(const bf16* __restrict__ A,
                                               const bf16* __restrict__ Bm,
                                               float* __restrict__ Cf,
                                               bf16* __restrict__ Cb,
                                               const float* __restrict__ bias,
                                               int M, int N, int K) {
  __shared__ __align__(16) bf16 As[128 * 64];
  __shared__ __align__(16) bf16 Bs[128 * 64];
  const int t = threadIdx.x;
  const int w = t >> 6, l = t & 63;
  const int wr = w >> 1, wc = w & 1;
  const int lr = l & 15, lh = l >> 4;
  const int bm = blockIdx.x * 128, bn = blockIdx.y * 128;
  // staging map: instr covers 8 rows x 8 chunks(16B). lane -> (row, chunk)
  const int srow = l >> 3;              // 0..7 within the 8-row group
  const int schunk = (l & 7) ^ srow;    // pre-swizzled global chunk index

  f32x4 acc[4][4] = {};

  for (int k0 = 0; k0 < K; k0 += 64) {
    __syncthreads();
#pragma unroll
    for (int jj = 0; jj < 4; ++jj) {
      const int j = w + jj * 4;          // 8-row group 0..15
      const int r = j * 8 + srow;
      gl_lds16(A + (size_t)(bm + r) * K + k0 + schunk * 8, As + j * 512);
      gl_lds16(Bm + (size_t)(bn + r) * K + k0 + schunk * 8, Bs + j * 512);
    }
    __syncthreads();
#pragma unroll
    for (int kk = 0; kk < 2; ++kk) {
      bf16x8 af[4], bfr[4];
#pragma unroll
      for (int mt = 0; mt < 4; ++mt)
        af[mt] = *(const bf16x8*)(As + swz(wr * 64 + mt * 16 + lr, kk * 32 + lh * 8));
#pragma unroll
      for (int nt = 0; nt < 4; ++nt)
        bfr[nt] = *(const bf16x8*)(Bs + swz(wc * 64 + nt * 16 + lr, kk * 32 + lh * 8));
#pragma unroll
      for (int mt = 0; mt < 4; ++mt)
#pragma unroll
        for (int nt = 0; nt < 4; ++nt)
          acc[mt][nt] = MFMA16(af[mt], bfr[nt], acc[mt][nt]);
    }
  }

#pragma unroll
  for (int mt = 0; mt < 4; ++mt)
#pragma unroll
    for (int nt = 0; nt < 4; ++nt)
#pragma unroll
      for (int r = 0; r < 4; ++r) {
        int m = bm + wr * 64 + mt * 16 + lh * 4 + r;
        int n = bn + wc * 64 + nt * 16 + lr;
        if (Cb) Cb[(size_t)m * N + n] = (bf16)acc[mt][nt][r];
        else    Cf[(size_t)m * N + n] = acc[mt][nt][r] + bias[n];
      }
}

// ---------------------------------------------------------------------------
// RoPE + repack. Q is pre-scaled by 0.125*log2(e) so attn scores are in the
// exp2 domain (v_exp_f32 native). K unscaled.
// ---------------------------------------------------------------------------
__global__ __launch_bounds__(256) void rope_repack(const bf16* __restrict__ qkv,
                                                   bf16* __restrict__ Qd,
                                                   bf16* __restrict__ Kd) {
  int idx = blockIdx.x * 256 + threadIdx.x;
  int j = idx & 31;
  int s = (idx >> 5) & 2047;
  int bh = idx >> 16;           // 0..31
  int b = bh >> 4, h = bh & 15;
  const bf16* row = qkv + (size_t)(b * 2048 + s) * 3072;
  int base = h * 64 + j;
  const float QS = 0.18033688011112042f;  // 0.125 * log2(e)
  float q1 = (float)row[base],        q2 = (float)row[base + 32];
  float k1 = (float)row[1024 + base], k2 = (float)row[1024 + base + 32];
  float inv_freq = expf((float)j * -0.28782313662425575f);
  float ang = (float)s * inv_freq;
  float c = cosf(ang), sn = sinf(ang);
  size_t o = ((size_t)bh * 2048 + s) * 64 + j;
  Qd[o]      = (bf16)((q1 * c - q2 * sn) * QS);
  Qd[o + 32] = (bf16)((q2 * c + q1 * sn) * QS);
  Kd[o]      = (bf16)(k1 * c - k2 * sn);
  Kd[o + 32] = (bf16)(k2 * c + k1 * sn);
}

// ---------------------------------------------------------------------------
// V transpose (once): qkv V-part -> Vt_g[bh][d][s].
// ---------------------------------------------------------------------------
__global__ __launch_bounds__(256) void v_transpose(const bf16* __restrict__ qkv,
                                                   bf16* __restrict__ Vtg) {
  const int bx = blockIdx.x;
  const int bh = bx >> 6, sc = bx & 63;
  const int b = bh >> 4, h = bh & 15;
  const int t = threadIdx.x;
  const int d = t & 63, w = t >> 6;
  const int s0 = sc * 32 + w * 8;
  bf16 vals[8];
#pragma unroll
  for (int e = 0; e < 8; ++e)
    vals[e] = qkv[(size_t)(b * 2048 + s0 + e) * 3072 + 2048 + h * 64 + d];
  *(bf16x8*)(Vtg + (size_t)bh * 131072 + (size_t)d * 2048 + s0) = *(bf16x8*)vals;
}

// ---------------------------------------------------------------------------
// Flash attention fwd. grid = (B*H=32, S/64=32). 256 thr = 4 waves.
// exp2-domain scores; lane-local l partials (reduced once in epilogue);
// skip-rescale when the running max doesn't grow (exact, THR=0).
// ---------------------------------------------------------------------------
__global__ __launch_bounds__(256) void attn_fwd(const bf16* __restrict__ Qg,
                                                const bf16* __restrict__ Kg,
                                                const bf16* __restrict__ Vtg,
                                                bf16* __restrict__ Og) {
  __shared__ __align__(16) bf16 Ks[64 * 64];
  __shared__ __align__(16) bf16 Vt[64 * 64];   // Vt[d][j] (kv-local), swizzled
  __shared__ __align__(16) bf16 Ps[64 * 64];
  const int bh = blockIdx.x, qt = blockIdx.y;
  const int t = threadIdx.x, w = t >> 6, l = t & 63;
  const int lr = l & 15, lh = l >> 4;
  const bf16* Qb  = Qg  + (size_t)bh * 2048 * 64;
  const bf16* Kb  = Kg  + (size_t)bh * 2048 * 64;
  const bf16* Vtb = Vtg + (size_t)bh * 131072;   // [64 d][2048 s]

  bf16x8 qf[2];
  {
    int qrow = qt * 64 + w * 16 + lr;
    qf[0] = *(const bf16x8*)(Qb + (size_t)qrow * 64 + lh * 8);
    qf[1] = *(const bf16x8*)(Qb + (size_t)qrow * 64 + lh * 8 + 32);
  }

  float mrow[4], lsum[4];
#pragma unroll
  for (int r = 0; r < 4; ++r) { mrow[r] = -INFINITY; lsum[r] = 0.f; }
  f32x4 acc[4] = {};

  const int r0 = t >> 2, c0 = (t & 3) * 16;
  for (int kv = 0; kv < 2048; kv += 64) {
    __syncthreads();
    *(bf16x8*)(Ks + swz(r0, c0))     = *(const bf16x8*)(Kb + (size_t)(kv + r0) * 64 + c0);
    *(bf16x8*)(Ks + swz(r0, c0 + 8)) = *(const bf16x8*)(Kb + (size_t)(kv + r0) * 64 + c0 + 8);
    *(bf16x8*)(Vt + swz(r0, c0))     = *(const bf16x8*)(Vtb + (size_t)r0 * 2048 + kv + c0);
    *(bf16x8*)(Vt + swz(r0, c0 + 8)) = *(const bf16x8*)(Vtb + (size_t)r0 * 2048 + kv + c0 + 8);
    __syncthreads();

    // scores S = Q K^T (16x64 per wave), already exp2-domain scaled
    f32x4 sc[4] = {};
#pragma unroll
    for (int kk = 0; kk < 2; ++kk) {
#pragma unroll
      for (int nt = 0; nt < 4; ++nt) {
        bf16x8 bfr = *(const bf16x8*)(Ks + swz(nt * 16 + lr, kk * 32 + lh * 8));
        sc[nt] = MFMA16(qf[kk], bfr, sc[nt]);
      }
    }

    // online softmax: rows i = lh*4 + r; lane owns 4 cols (nt*16 + lr)
#pragma unroll
    for (int r = 0; r < 4; ++r) {
      float s0 = sc[0][r], s1 = sc[1][r], s2 = sc[2][r], s3 = sc[3][r];
      float mx = fmaxf(fmaxf(s0, s1), fmaxf(s2, s3));
#pragma unroll
      for (int off = 1; off < 16; off <<= 1)
        mx = fmaxf(mx, __shfl_xor(mx, off, 16));
      if (mx > mrow[r]) {           // rescale only when the max grows (exact)
        float al = exp2f(mrow[r] - mx);
        mrow[r] = mx;
        lsum[r] *= al;
#pragma unroll
        for (int nt = 0; nt < 4; ++nt) acc[nt][r] *= al;
      }
      float p0 = exp2f(s0 - mrow[r]), p1 = exp2f(s1 - mrow[r]);
      float p2 = exp2f(s2 - mrow[r]), p3 = exp2f(s3 - mrow[r]);
      lsum[r] += (p0 + p1) + (p2 + p3);   // lane-local partial; reduce at end
      int prow = w * 16 + lh * 4 + r;
      Ps[swz(prow, lr)]      = (bf16)p0;
      Ps[swz(prow, 16 + lr)] = (bf16)p1;
      Ps[swz(prow, 32 + lr)] = (bf16)p2;
      Ps[swz(prow, 48 + lr)] = (bf16)p3;
    }
    asm volatile("s_waitcnt lgkmcnt(0)" ::: "memory");

    // O += P V
#pragma unroll
    for (int kk = 0; kk < 2; ++kk) {
      bf16x8 pa = *(const bf16x8*)(Ps + swz(w * 16 + lr, kk * 32 + lh * 8));
#pragma unroll
      for (int nt = 0; nt < 4; ++nt) {
        bf16x8 bv = *(const bf16x8*)(Vt + swz(nt * 16 + lr, kk * 32 + lh * 8));
        acc[nt] = MFMA16(pa, bv, acc[nt]);
      }
    }
  }

  // epilogue: reduce lane-local l partials across the 16-lane row group
  const int b = bh >> 4, h = bh & 15;
#pragma unroll
  for (int r = 0; r < 4; ++r) {
    float s = lsum[r];
#pragma unroll
    for (int off = 1; off < 16; off <<= 1)
      s += __shfl_xor(s, off, 16);
    lsum[r] = 1.0f / s;
  }
#pragma unroll
  for (int nt = 0; nt < 4; ++nt)
#pragma unroll
    for (int r = 0; r < 4; ++r) {
      int row = qt * 64 + w * 16 + lh * 4 + r;
      int col = h * 64 + nt * 16 + lr;
      Og[((size_t)(b * 2048 + row)) * 1024 + col] = (bf16)(acc[nt][r] * lsum[r]);
    }
}

// ---------------------------------------------------------------------------
extern "C" void kernel_launch(void* const* d_in, const int* in_sizes, int n_in,
                              void* d_out, int out_size, void* d_ws, size_t ws_size,
                              hipStream_t stream) {
  const float* x     = (const float*)d_in[0];  // [2,2048,1024]
  const float* w_qkv = (const float*)d_in[1];  // [3072,1024]
  const float* w_out = (const float*)d_in[2];  // [1024,1024]
  const float* b_out = (const float*)d_in[3];  // [1024]
  float* out = (float*)d_out;
  char* ws = (char*)d_ws;
  const size_t MB = 1024 * 1024;

  bf16* xb    = (bf16*)(ws);            // 8 MB (x bf16)
  bf16* wqkvb = (bf16*)(ws + 8 * MB);   // 6 MB
  bf16* woutb = (bf16*)(ws + 14 * MB);  // 2 MB
  bf16* qkvb  = (bf16*)(ws + 16 * MB);  // 24 MB
  bf16* Qd    = (bf16*)(ws + 40 * MB);  // 8 MB
  bf16* Kd    = (bf16*)(ws + 48 * MB);  // 8 MB
  bf16* Vtg   = (bf16*)(ws + 56 * MB);  // 8 MB  V^T [bh][d][s]
  bf16* attnb = xb;                     // reuse x slot after gemm_qkv consumed it

  cvt_f32_bf16<<<4096, 256, 0, stream>>>(x, xb, 1048576);
  cvt_f32_bf16<<<3072, 256, 0, stream>>>(w_qkv, wqkvb, 786432);
  cvt_f32_bf16<<<1024, 256, 0, stream>>>(w_out, woutb, 262144);

  // qkv = x @ w_qkv^T : M=4096, N=3072, K=1024  -> bf16
  gemm_bt<<<dim3(32, 24), 256, 0, stream>>>(xb, wqkvb, nullptr, qkvb, nullptr,
                                            4096, 3072, 1024);
  rope_repack<<<8192, 256, 0, stream>>>(qkvb, Qd, Kd);
  v_transpose<<<2048, 256, 0, stream>>>(qkvb, Vtg);
  attn_fwd<<<dim3(32, 32), 256, 0, stream>>>(Qd, Kd, Vtg, attnb);
  // out = attn @ w_out^T + b : M=4096, N=1024, K=1024 -> f32
  gemm_bt<<<dim3(32, 8), 256, 0, stream>>>(attnb, woutb, out, nullptr, b_out,
                                           4096, 1024, 1024);
}

// Round 8
// 202.136 us; speedup vs baseline: 1.1112x; 1.1112x over previous
//
#include <hip/hip_runtime.h>
#include <hip/hip_bf16.h>
#include <math.h>

typedef __bf16 bf16;
typedef __attribute__((ext_vector_type(8))) __bf16 bf16x8;
typedef __attribute__((ext_vector_type(4))) __bf16 bf16x4;
typedef __attribute__((ext_vector_type(4))) float f32x4;

#define MFMA16(a, b, c) __builtin_amdgcn_mfma_f32_16x16x32_bf16((a), (b), (c), 0, 0, 0)

// raw v_exp_f32 (2^x), no libm guard code
__device__ __forceinline__ float fexp2(float x) { return __builtin_amdgcn_exp2f(x); }

// XOR swizzle for [rows][64] bf16 LDS tiles (128 B row = 32 banks exactly).
__device__ __forceinline__ int swz(int row, int col) {
  return row * 64 + ((((col) >> 3) ^ (row & 7)) << 3) + (col & 7);
}

// async global->LDS, 16B per lane. LDS dest is wave-uniform base + lane*16.
__device__ __forceinline__ void gl_lds16(const bf16* g, bf16* l) {
  __builtin_amdgcn_global_load_lds(
      (const __attribute__((address_space(1))) void*)g,
      (__attribute__((address_space(3))) void*)l, 16, 0, 0);
}

// ---------------------------------------------------------------------------
// f32 -> bf16 cast, 4 elems/thread
// ---------------------------------------------------------------------------
__global__ __launch_bounds__(256) void cvt_f32_bf16(const float* __restrict__ in,
                                                    bf16* __restrict__ out, int n4) {
  int i = blockIdx.x * 256 + threadIdx.x;
  if (i < n4) {
    float4 v = ((const float4*)in)[i];
    bf16x4 o = {(bf16)v.x, (bf16)v.y, (bf16)v.z, (bf16)v.w};
    ((bf16x4*)out)[i] = o;
  }
}

// ---------------------------------------------------------------------------
// GEMM, C[m,n] = sum_k A[m,k]*B[n,k]  (both row-major, "B^T" layout)
// BM=BN=128, BK=64, 256 threads = 4 waves in 2x2, each wave 64x64 out.
// Staging via global_load_lds (linear LDS dest, pre-swizzled global src);
// reads use XOR swizzle -> conflict-free both sides.
// ---------------------------------------------------------------------------
__global__ __launch_bounds__(256) void gemm_bt(const bf16* __restrict__ A,
                                               const bf16* __restrict__ Bm,
                                               float* __restrict__ Cf,
                                               bf16* __restrict__ Cb,
                                               const float* __restrict__ bias,
                                               int M, int N, int K) {
  __shared__ __align__(16) bf16 As[128 * 64];
  __shared__ __align__(16) bf16 Bs[128 * 64];
  const int t = threadIdx.x;
  const int w = t >> 6, l = t & 63;
  const int wr = w >> 1, wc = w & 1;
  const int lr = l & 15, lh = l >> 4;
  const int bm = blockIdx.x * 128, bn = blockIdx.y * 128;
  const int srow = l >> 3;              // 0..7 within the 8-row group
  const int schunk = (l & 7) ^ srow;    // pre-swizzled global chunk index

  f32x4 acc[4][4] = {};

  for (int k0 = 0; k0 < K; k0 += 64) {
    __syncthreads();
#pragma unroll
    for (int jj = 0; jj < 4; ++jj) {
      const int j = w + jj * 4;          // 8-row group 0..15
      const int r = j * 8 + srow;
      gl_lds16(A + (size_t)(bm + r) * K + k0 + schunk * 8, As + j * 512);
      gl_lds16(Bm + (size_t)(bn + r) * K + k0 + schunk * 8, Bs + j * 512);
    }
    __syncthreads();
#pragma unroll
    for (int kk = 0; kk < 2; ++kk) {
      bf16x8 af[4], bfr[4];
#pragma unroll
      for (int mt = 0; mt < 4; ++mt)
        af[mt] = *(const bf16x8*)(As + swz(wr * 64 + mt * 16 + lr, kk * 32 + lh * 8));
#pragma unroll
      for (int nt = 0; nt < 4; ++nt)
        bfr[nt] = *(const bf16x8*)(Bs + swz(wc * 64 + nt * 16 + lr, kk * 32 + lh * 8));
#pragma unroll
      for (int mt = 0; mt < 4; ++mt)
#pragma unroll
        for (int nt = 0; nt < 4; ++nt)
          acc[mt][nt] = MFMA16(af[mt], bfr[nt], acc[mt][nt]);
    }
  }

#pragma unroll
  for (int mt = 0; mt < 4; ++mt)
#pragma unroll
    for (int nt = 0; nt < 4; ++nt)
#pragma unroll
      for (int r = 0; r < 4; ++r) {
        int m = bm + wr * 64 + mt * 16 + lh * 4 + r;
        int n = bn + wc * 64 + nt * 16 + lr;
        if (Cb) Cb[(size_t)m * N + n] = (bf16)acc[mt][nt][r];
        else    Cf[(size_t)m * N + n] = acc[mt][nt][r] + bias[n];
      }
}

// ---------------------------------------------------------------------------
// RoPE + repack. Q is pre-scaled by 0.125*log2(e) so attn scores are in the
// exp2 domain (v_exp_f32 native). K unscaled.
// ---------------------------------------------------------------------------
__global__ __launch_bounds__(256) void rope_repack(const bf16* __restrict__ qkv,
                                                   bf16* __restrict__ Qd,
                                                   bf16* __restrict__ Kd) {
  int idx = blockIdx.x * 256 + threadIdx.x;
  int j = idx & 31;
  int s = (idx >> 5) & 2047;
  int bh = idx >> 16;           // 0..31
  int b = bh >> 4, h = bh & 15;
  const bf16* row = qkv + (size_t)(b * 2048 + s) * 3072;
  int base = h * 64 + j;
  const float QS = 0.18033688011112042f;  // 0.125 * log2(e)
  float q1 = (float)row[base],        q2 = (float)row[base + 32];
  float k1 = (float)row[1024 + base], k2 = (float)row[1024 + base + 32];
  float inv_freq = expf((float)j * -0.28782313662425575f);
  float ang = (float)s * inv_freq;
  float c = cosf(ang), sn = sinf(ang);
  size_t o = ((size_t)bh * 2048 + s) * 64 + j;
  Qd[o]      = (bf16)((q1 * c - q2 * sn) * QS);
  Qd[o + 32] = (bf16)((q2 * c + q1 * sn) * QS);
  Kd[o]      = (bf16)(k1 * c - k2 * sn);
  Kd[o + 32] = (bf16)(k2 * c + k1 * sn);
}

// ---------------------------------------------------------------------------
// V transpose (once): qkv V-part -> Vt_g[bh][d][s].
// ---------------------------------------------------------------------------
__global__ __launch_bounds__(256) void v_transpose(const bf16* __restrict__ qkv,
                                                   bf16* __restrict__ Vtg) {
  const int bx = blockIdx.x;
  const int bh = bx >> 6, sc = bx & 63;
  const int b = bh >> 4, h = bh & 15;
  const int t = threadIdx.x;
  const int d = t & 63, w = t >> 6;
  const int s0 = sc * 32 + w * 8;
  bf16 vals[8];
#pragma unroll
  for (int e = 0; e < 8; ++e)
    vals[e] = qkv[(size_t)(b * 2048 + s0 + e) * 3072 + 2048 + h * 64 + d];
  *(bf16x8*)(Vtg + (size_t)bh * 131072 + (size_t)d * 2048 + s0) = *(bf16x8*)vals;
}

// ---------------------------------------------------------------------------
// Flash attention fwd. grid = (B*H=32, S/64=32). 256 thr = 4 waves.
// exp2-domain scores via raw v_exp_f32; lane-local l partials; skip-rescale
// when the running max doesn't grow (exact, THR=0).
// ---------------------------------------------------------------------------
__global__ __launch_bounds__(256) void attn_fwd(const bf16* __restrict__ Qg,
                                                const bf16* __restrict__ Kg,
                                                const bf16* __restrict__ Vtg,
                                                bf16* __restrict__ Og) {
  __shared__ __align__(16) bf16 Ks[64 * 64];
  __shared__ __align__(16) bf16 Vt[64 * 64];   // Vt[d][j] (kv-local), swizzled
  __shared__ __align__(16) bf16 Ps[64 * 64];
  const int bh = blockIdx.x, qt = blockIdx.y;
  const int t = threadIdx.x, w = t >> 6, l = t & 63;
  const int lr = l & 15, lh = l >> 4;
  const bf16* Qb  = Qg  + (size_t)bh * 2048 * 64;
  const bf16* Kb  = Kg  + (size_t)bh * 2048 * 64;
  const bf16* Vtb = Vtg + (size_t)bh * 131072;   // [64 d][2048 s]

  bf16x8 qf[2];
  {
    int qrow = qt * 64 + w * 16 + lr;
    qf[0] = *(const bf16x8*)(Qb + (size_t)qrow * 64 + lh * 8);
    qf[1] = *(const bf16x8*)(Qb + (size_t)qrow * 64 + lh * 8 + 32);
  }

  float mrow[4], lsum[4];
#pragma unroll
  for (int r = 0; r < 4; ++r) { mrow[r] = -INFINITY; lsum[r] = 0.f; }
  f32x4 acc[4] = {};

  const int r0 = t >> 2, c0 = (t & 3) * 16;
  for (int kv = 0; kv < 2048; kv += 64) {
    __syncthreads();
    *(bf16x8*)(Ks + swz(r0, c0))     = *(const bf16x8*)(Kb + (size_t)(kv + r0) * 64 + c0);
    *(bf16x8*)(Ks + swz(r0, c0 + 8)) = *(const bf16x8*)(Kb + (size_t)(kv + r0) * 64 + c0 + 8);
    *(bf16x8*)(Vt + swz(r0, c0))     = *(const bf16x8*)(Vtb + (size_t)r0 * 2048 + kv + c0);
    *(bf16x8*)(Vt + swz(r0, c0 + 8)) = *(const bf16x8*)(Vtb + (size_t)r0 * 2048 + kv + c0 + 8);
    __syncthreads();

    // scores S = Q K^T (16x64 per wave), already exp2-domain scaled
    f32x4 sc[4] = {};
#pragma unroll
    for (int kk = 0; kk < 2; ++kk) {
#pragma unroll
      for (int nt = 0; nt < 4; ++nt) {
        bf16x8 bfr = *(const bf16x8*)(Ks + swz(nt * 16 + lr, kk * 32 + lh * 8));
        sc[nt] = MFMA16(qf[kk], bfr, sc[nt]);
      }
    }

    // online softmax: rows i = lh*4 + r; lane owns 4 cols (nt*16 + lr)
#pragma unroll
    for (int r = 0; r < 4; ++r) {
      float s0 = sc[0][r], s1 = sc[1][r], s2 = sc[2][r], s3 = sc[3][r];
      float mx = fmaxf(fmaxf(s0, s1), fmaxf(s2, s3));
#pragma unroll
      for (int off = 1; off < 16; off <<= 1)
        mx = fmaxf(mx, __shfl_xor(mx, off, 16));
      if (mx > mrow[r]) {           // rescale only when the max grows (exact)
        float al = fexp2(mrow[r] - mx);
        mrow[r] = mx;
        lsum[r] *= al;
#pragma unroll
        for (int nt = 0; nt < 4; ++nt) acc[nt][r] *= al;
      }
      float p0 = fexp2(s0 - mrow[r]), p1 = fexp2(s1 - mrow[r]);
      float p2 = fexp2(s2 - mrow[r]), p3 = fexp2(s3 - mrow[r]);
      lsum[r] += (p0 + p1) + (p2 + p3);   // lane-local partial; reduce at end
      int prow = w * 16 + lh * 4 + r;
      Ps[swz(prow, lr)]      = (bf16)p0;
      Ps[swz(prow, 16 + lr)] = (bf16)p1;
      Ps[swz(prow, 32 + lr)] = (bf16)p2;
      Ps[swz(prow, 48 + lr)] = (bf16)p3;
    }
    asm volatile("s_waitcnt lgkmcnt(0)" ::: "memory");

    // O += P V
#pragma unroll
    for (int kk = 0; kk < 2; ++kk) {
      bf16x8 pa = *(const bf16x8*)(Ps + swz(w * 16 + lr, kk * 32 + lh * 8));
#pragma unroll
      for (int nt = 0; nt < 4; ++nt) {
        bf16x8 bv = *(const bf16x8*)(Vt + swz(nt * 16 + lr, kk * 32 + lh * 8));
        acc[nt] = MFMA16(pa, bv, acc[nt]);
      }
    }
  }

  // epilogue: reduce lane-local l partials across the 16-lane row group
  const int b = bh >> 4, h = bh & 15;
#pragma unroll
  for (int r = 0; r < 4; ++r) {
    float s = lsum[r];
#pragma unroll
    for (int off = 1; off < 16; off <<= 1)
      s += __shfl_xor(s, off, 16);
    lsum[r] = 1.0f / s;
  }
#pragma unroll
  for (int nt = 0; nt < 4; ++nt)
#pragma unroll
    for (int r = 0; r < 4; ++r) {
      int row = qt * 64 + w * 16 + lh * 4 + r;
      int col = h * 64 + nt * 16 + lr;
      Og[((size_t)(b * 2048 + row)) * 1024 + col] = (bf16)(acc[nt][r] * lsum[r]);
    }
}

// ---------------------------------------------------------------------------
extern "C" void kernel_launch(void* const* d_in, const int* in_sizes, int n_in,
                              void* d_out, int out_size, void* d_ws, size_t ws_size,
                              hipStream_t stream) {
  const float* x     = (const float*)d_in[0];  // [2,2048,1024]
  const float* w_qkv = (const float*)d_in[1];  // [3072,1024]
  const float* w_out = (const float*)d_in[2];  // [1024,1024]
  const float* b_out = (const float*)d_in[3];  // [1024]
  float* out = (float*)d_out;
  char* ws = (char*)d_ws;
  const size_t MB = 1024 * 1024;

  bf16* xb    = (bf16*)(ws);            // 8 MB (x bf16)
  bf16* wqkvb = (bf16*)(ws + 8 * MB);   // 6 MB
  bf16* woutb = (bf16*)(ws + 14 * MB);  // 2 MB
  bf16* qkvb  = (bf16*)(ws + 16 * MB);  // 24 MB
  bf16* Qd    = (bf16*)(ws + 40 * MB);  // 8 MB
  bf16* Kd    = (bf16*)(ws + 48 * MB);  // 8 MB
  bf16* Vtg   = (bf16*)(ws + 56 * MB);  // 8 MB  V^T [bh][d][s]
  bf16* attnb = xb;                     // reuse x slot after gemm_qkv consumed it

  cvt_f32_bf16<<<4096, 256, 0, stream>>>(x, xb, 1048576);
  cvt_f32_bf16<<<3072, 256, 0, stream>>>(w_qkv, wqkvb, 786432);
  cvt_f32_bf16<<<1024, 256, 0, stream>>>(w_out, woutb, 262144);

  // qkv = x @ w_qkv^T : M=4096, N=3072, K=1024  -> bf16
  gemm_bt<<<dim3(32, 24), 256, 0, stream>>>(xb, wqkvb, nullptr, qkvb, nullptr,
                                            4096, 3072, 1024);
  rope_repack<<<8192, 256, 0, stream>>>(qkvb, Qd, Kd);
  v_transpose<<<2048, 256, 0, stream>>>(qkvb, Vtg);
  attn_fwd<<<dim3(32, 32), 256, 0, stream>>>(Qd, Kd, Vtg, attnb);
  // out = attn @ w_out^T + b : M=4096, N=1024, K=1024 -> f32
  gemm_bt<<<dim3(32, 8), 256, 0, stream>>>(attnb, woutb, out, nullptr, b_out,
                                           4096, 1024, 1024);
}

// Round 11
// 147.729 us; speedup vs baseline: 1.5205x; 1.3683x over previous
//
#include <hip/hip_runtime.h>
#include <hip/hip_bf16.h>
#include <math.h>

typedef __bf16 bf16;
typedef __attribute__((ext_vector_type(8))) __bf16 bf16x8;
typedef __attribute__((ext_vector_type(4))) __bf16 bf16x4;
typedef __attribute__((ext_vector_type(4))) float f32x4;
typedef __attribute__((ext_vector_type(16))) float f32x16;

#define MFMA16(a, b, c) __builtin_amdgcn_mfma_f32_16x16x32_bf16((a), (b), (c), 0, 0, 0)
#define MFMA32(a, b, c) __builtin_amdgcn_mfma_f32_32x32x16_bf16((a), (b), (c), 0, 0, 0)

// raw v_exp_f32 (2^x), no libm guard code
__device__ __forceinline__ float fexp2(float x) { return __builtin_amdgcn_exp2f(x); }

// XOR swizzle for [rows][64] bf16 LDS tiles (128 B row = 32 banks exactly).
__device__ __forceinline__ int swz(int row, int col) {
  return row * 64 + ((((col) >> 3) ^ (row & 7)) << 3) + (col & 7);
}

// async global->LDS, 16B per lane. LDS dest is wave-uniform base + lane*16.
__device__ __forceinline__ void gl_lds16(const bf16* g, bf16* l) {
  __builtin_amdgcn_global_load_lds(
      (const __attribute__((address_space(1))) void*)g,
      (__attribute__((address_space(3))) void*)l, 16, 0, 0);
}

// ---------------------------------------------------------------------------
// f32 -> bf16 cast, 4 elems/thread
// ---------------------------------------------------------------------------
__global__ __launch_bounds__(256) void cvt_f32_bf16(const float* __restrict__ in,
                                                    bf16* __restrict__ out, int n4) {
  int i = blockIdx.x * 256 + threadIdx.x;
  if (i < n4) {
    float4 v = ((const float4*)in)[i];
    bf16x4 o = {(bf16)v.x, (bf16)v.y, (bf16)v.z, (bf16)v.w};
    ((bf16x4*)out)[i] = o;
  }
}

// ---------------------------------------------------------------------------
// GEMM, C[m,n] = sum_k A[m,k]*B[n,k]  (both row-major, "B^T" layout)
// ---------------------------------------------------------------------------
__global__ __launch_bounds__(256) void gemm_bt(const bf16* __restrict__ A,
                                               const bf16* __restrict__ Bm,
                                               float* __restrict__ Cf,
                                               bf16* __restrict__ Cb,
                                               const float* __restrict__ bias,
                                               int M, int N, int K) {
  __shared__ __align__(16) bf16 As[128 * 64];
  __shared__ __align__(16) bf16 Bs[128 * 64];
  const int t = threadIdx.x;
  const int w = t >> 6, l = t & 63;
  const int wr = w >> 1, wc = w & 1;
  const int lr = l & 15, lh = l >> 4;
  const int bm = blockIdx.x * 128, bn = blockIdx.y * 128;
  const int srow = l >> 3;              // 0..7 within the 8-row group
  const int schunk = (l & 7) ^ srow;    // pre-swizzled global chunk index

  f32x4 acc[4][4] = {};

  for (int k0 = 0; k0 < K; k0 += 64) {
    __syncthreads();
#pragma unroll
    for (int jj = 0; jj < 4; ++jj) {
      const int j = w + jj * 4;          // 8-row group 0..15
      const int r = j * 8 + srow;
      gl_lds16(A + (size_t)(bm + r) * K + k0 + schunk * 8, As + j * 512);
      gl_lds16(Bm + (size_t)(bn + r) * K + k0 + schunk * 8, Bs + j * 512);
    }
    __syncthreads();
#pragma unroll
    for (int kk = 0; kk < 2; ++kk) {
      bf16x8 af[4], bfr[4];
#pragma unroll
      for (int mt = 0; mt < 4; ++mt)
        af[mt] = *(const bf16x8*)(As + swz(wr * 64 + mt * 16 + lr, kk * 32 + lh * 8));
#pragma unroll
      for (int nt = 0; nt < 4; ++nt)
        bfr[nt] = *(const bf16x8*)(Bs + swz(wc * 64 + nt * 16 + lr, kk * 32 + lh * 8));
#pragma unroll
      for (int mt = 0; mt < 4; ++mt)
#pragma unroll
        for (int nt = 0; nt < 4; ++nt)
          acc[mt][nt] = MFMA16(af[mt], bfr[nt], acc[mt][nt]);
    }
  }

#pragma unroll
  for (int mt = 0; mt < 4; ++mt)
#pragma unroll
    for (int nt = 0; nt < 4; ++nt)
#pragma unroll
      for (int r = 0; r < 4; ++r) {
        int m = bm + wr * 64 + mt * 16 + lh * 4 + r;
        int n = bn + wc * 64 + nt * 16 + lr;
        if (Cb) Cb[(size_t)m * N + n] = (bf16)acc[mt][nt][r];
        else    Cf[(size_t)m * N + n] = acc[mt][nt][r] + bias[n];
      }
}

// ---------------------------------------------------------------------------
// RoPE + repack. Q pre-scaled by 0.125*log2(e) -> exp2-domain scores.
// ---------------------------------------------------------------------------
__global__ __launch_bounds__(256) void rope_repack(const bf16* __restrict__ qkv,
                                                   bf16* __restrict__ Qd,
                                                   bf16* __restrict__ Kd) {
  int idx = blockIdx.x * 256 + threadIdx.x;
  int j = idx & 31;
  int s = (idx >> 5) & 2047;
  int bh = idx >> 16;           // 0..31
  int b = bh >> 4, h = bh & 15;
  const bf16* row = qkv + (size_t)(b * 2048 + s) * 3072;
  int base = h * 64 + j;
  const float QS = 0.18033688011112042f;  // 0.125 * log2(e)
  float q1 = (float)row[base],        q2 = (float)row[base + 32];
  float k1 = (float)row[1024 + base], k2 = (float)row[1024 + base + 32];
  float inv_freq = expf((float)j * -0.28782313662425575f);
  float ang = (float)s * inv_freq;
  float c = cosf(ang), sn = sinf(ang);
  size_t o = ((size_t)bh * 2048 + s) * 64 + j;
  Qd[o]      = (bf16)((q1 * c - q2 * sn) * QS);
  Qd[o + 32] = (bf16)((q2 * c + q1 * sn) * QS);
  Kd[o]      = (bf16)(k1 * c - k2 * sn);
  Kd[o + 32] = (bf16)(k2 * c + k1 * sn);
}

// ---------------------------------------------------------------------------
// V transpose (once): qkv V-part -> Vt_g[bh][d][s].
// ---------------------------------------------------------------------------
__global__ __launch_bounds__(256) void v_transpose(const bf16* __restrict__ qkv,
                                                   bf16* __restrict__ Vtg) {
  const int bx = blockIdx.x;
  const int bh = bx >> 6, sc = bx & 63;
  const int b = bh >> 4, h = bh & 15;
  const int t = threadIdx.x;
  const int d = t & 63, w = t >> 6;
  const int s0 = sc * 32 + w * 8;
  bf16 vals[8];
#pragma unroll
  for (int e = 0; e < 8; ++e)
    vals[e] = qkv[(size_t)(b * 2048 + s0 + e) * 3072 + 2048 + h * 64 + d];
  *(bf16x8*)(Vtg + (size_t)bh * 131072 + (size_t)d * 2048 + s0) = *(bf16x8*)vals;
}

// ---------------------------------------------------------------------------
// Flash attention fwd, swapped-operand 32x32 form — NO cross-lane P shuffle.
//
// S^T = mfma32(K, Q): lane holds P[kv=(j&3)+8*(j>>2)+4*hi][q=lane&31].
// PV B-frag (step s): lane's OWN p-values p[8*(s&1)+e] (+p1 block for s>=2);
// its slot->kv map is c(hi,e) = 16s + 4hi + (e&3) + 8*(e>>2).
// The V A-frag is made to use the SAME map by interleaving Vt's staging:
// within each 16-col block, new cols = old {0-3,8-11 | 4-7,12-15}, so a
// contiguous b128 read at col 16s+8hi delivers exactly V^T[d][c(hi,0..7)].
// (Any common A/B slot->k bijection cancels in MFMA.)
// Cross-lane only for max/lsum via __shfl_xor(x,32) (certain semantics).
// ---------------------------------------------------------------------------
__global__ __launch_bounds__(256) void attn_fwd(const bf16* __restrict__ Qg,
                                                const bf16* __restrict__ Kg,
                                                const bf16* __restrict__ Vtg,
                                                bf16* __restrict__ Og) {
  __shared__ __align__(16) bf16 Ks[64 * 64];
  __shared__ __align__(16) bf16 Vt[64 * 64];   // interleaved-swizzled V^T tile
  const int bh = blockIdx.x, qt = blockIdx.y;
  const int t = threadIdx.x, wv = t >> 6, l = t & 63;
  const int lq = l & 31, hi = l >> 5;
  const bf16* Qb  = Qg  + (size_t)bh * 2048 * 64;
  const bf16* Kb  = Kg  + (size_t)bh * 2048 * 64;
  const bf16* Vtb = Vtg + (size_t)bh * 131072;   // [64 d][2048 s]
  const int q = qt * 128 + wv * 32 + lq;

  // Q B-frags: col=q(lane), k = d = s*16 + hi*8 + e (same map as K A-frag)
  bf16x8 qf[4];
#pragma unroll
  for (int s = 0; s < 4; ++s)
    qf[s] = *(const bf16x8*)(Qb + (size_t)q * 64 + s * 16 + hi * 8);

  f32x16 o0 = {}, o1 = {};          // O^T: d = dblk*32 + (j&3)+8*(j>>2)+4*hi
  float mrow = -INFINITY, lsum = 0.f;

  const int r0 = t >> 2, c0 = (t & 3) * 16;
  for (int kv = 0; kv < 2048; kv += 64) {
    __syncthreads();
    *(bf16x8*)(Ks + swz(r0, c0))     = *(const bf16x8*)(Kb + (size_t)(kv + r0) * 64 + c0);
    *(bf16x8*)(Ks + swz(r0, c0 + 8)) = *(const bf16x8*)(Kb + (size_t)(kv + r0) * 64 + c0 + 8);
    {
      // Vt staging with middle-4-group interleave (register-only)
      bf16x8 vA = *(const bf16x8*)(Vtb + (size_t)r0 * 2048 + kv + c0);
      bf16x8 vB = *(const bf16x8*)(Vtb + (size_t)r0 * 2048 + kv + c0 + 8);
      bf16x8 w0, w1;
#pragma unroll
      for (int e = 0; e < 4; ++e) {
        w0[e] = vA[e];     w0[4 + e] = vB[e];
        w1[e] = vA[4 + e]; w1[4 + e] = vB[4 + e];
      }
      *(bf16x8*)(Vt + swz(r0, c0))     = w0;
      *(bf16x8*)(Vt + swz(r0, c0 + 8)) = w1;
    }
    __syncthreads();

    // S^T = K x Q : p0/p1 hold kv-blocks 0/1; per lane 32 scores of its q
    f32x16 p0 = {}, p1 = {};
#pragma unroll
    for (int s = 0; s < 4; ++s) {
      bf16x8 ka0 = *(const bf16x8*)(Ks + swz(lq,      s * 16 + hi * 8));
      bf16x8 ka1 = *(const bf16x8*)(Ks + swz(32 + lq, s * 16 + hi * 8));
      p0 = MFMA32(ka0, qf[s], p0);
      p1 = MFMA32(ka1, qf[s], p1);
    }

    // lane-local max over 32 + partner (lane^32) via shfl
    float m0 = fmaxf(p0[0], p0[1]),  m1 = fmaxf(p0[2], p0[3]);
    float m2 = fmaxf(p0[4], p0[5]),  m3 = fmaxf(p0[6], p0[7]);
#pragma unroll
    for (int j = 8; j < 16; j += 4) {
      m0 = fmaxf(m0, fmaxf(p0[j], p0[j + 1]));
      m1 = fmaxf(m1, fmaxf(p0[j + 2], p0[j + 3]));
    }
#pragma unroll
    for (int j = 0; j < 16; j += 4) {
      m2 = fmaxf(m2, fmaxf(p1[j], p1[j + 1]));
      m3 = fmaxf(m3, fmaxf(p1[j + 2], p1[j + 3]));
    }
    float mx = fmaxf(fmaxf(m0, m1), fmaxf(m2, m3));
    mx = fmaxf(mx, __shfl_xor(mx, 32));
    if (mx > mrow) {                  // rescale only when the max grows (exact)
      float al = fexp2(mrow - mx);
      mrow = mx;
      lsum *= al;
#pragma unroll
      for (int j = 0; j < 16; ++j) { o0[j] *= al; o1[j] *= al; }
    }
#pragma unroll
    for (int j = 0; j < 16; ++j) {
      p0[j] = fexp2(p0[j] - mrow);
      p1[j] = fexp2(p1[j] - mrow);
    }
    float l0 = 0.f, l1 = 0.f, l2 = 0.f, l3 = 0.f;
#pragma unroll
    for (int j = 0; j < 16; j += 4) {
      l0 += p0[j]; l1 += p0[j + 1]; l2 += p0[j + 2]; l3 += p0[j + 3];
      l0 += p1[j]; l1 += p1[j + 1]; l2 += p1[j + 2]; l3 += p1[j + 3];
    }
    lsum += (l0 + l1) + (l2 + l3);

    // O^T += V^T x P : 4 k-steps of 16 kv; B-frag = lane's OWN p-values
#pragma unroll
    for (int s = 0; s < 4; ++s) {
      bf16x8 pb;
#pragma unroll
      for (int e = 0; e < 8; ++e) {
        float pv = (s == 0) ? p0[e] : (s == 1) ? p0[8 + e]
                 : (s == 2) ? p1[e] : p1[8 + e];
        pb[e] = (bf16)pv;
      }
      bf16x8 va0 = *(const bf16x8*)(Vt + swz(lq,      s * 16 + hi * 8));
      bf16x8 va1 = *(const bf16x8*)(Vt + swz(32 + lq, s * 16 + hi * 8));
      o0 = MFMA32(va0, pb, o0);
      o1 = MFMA32(va1, pb, o1);
    }
  }

  // epilogue: combine partner lsum, write O (lane owns q = its own row)
  float inv = 1.0f / (lsum + __shfl_xor(lsum, 32));
  const int b = bh >> 4, h = bh & 15;
  bf16* orow = Og + (size_t)(b * 2048 + q) * 1024 + h * 64;
#pragma unroll
  for (int dblk = 0; dblk < 2; ++dblk) {
#pragma unroll
    for (int J = 0; J < 4; ++J) {
      float e0 = (dblk ? o1[4 * J] : o0[4 * J]) * inv;
      float e1 = (dblk ? o1[4 * J + 1] : o0[4 * J + 1]) * inv;
      float e2 = (dblk ? o1[4 * J + 2] : o0[4 * J + 2]) * inv;
      float e3 = (dblk ? o1[4 * J + 3] : o0[4 * J + 3]) * inv;
      bf16x4 wv = {(bf16)e0, (bf16)e1, (bf16)e2, (bf16)e3};
      *(bf16x4*)(orow + dblk * 32 + 8 * J + 4 * hi) = wv;
    }
  }
}

// ---------------------------------------------------------------------------
extern "C" void kernel_launch(void* const* d_in, const int* in_sizes, int n_in,
                              void* d_out, int out_size, void* d_ws, size_t ws_size,
                              hipStream_t stream) {
  const float* x     = (const float*)d_in[0];  // [2,2048,1024]
  const float* w_qkv = (const float*)d_in[1];  // [3072,1024]
  const float* w_out = (const float*)d_in[2];  // [1024,1024]
  const float* b_out = (const float*)d_in[3];  // [1024]
  float* out = (float*)d_out;
  char* ws = (char*)d_ws;
  const size_t MB = 1024 * 1024;

  bf16* xb    = (bf16*)(ws);            // 8 MB (x bf16)
  bf16* wqkvb = (bf16*)(ws + 8 * MB);   // 6 MB
  bf16* woutb = (bf16*)(ws + 14 * MB);  // 2 MB
  bf16* qkvb  = (bf16*)(ws + 16 * MB);  // 24 MB
  bf16* Qd    = (bf16*)(ws + 40 * MB);  // 8 MB
  bf16* Kd    = (bf16*)(ws + 48 * MB);  // 8 MB
  bf16* Vtg   = (bf16*)(ws + 56 * MB);  // 8 MB  V^T [bh][d][s]
  bf16* attnb = xb;                     // reuse x slot after gemm_qkv consumed it

  cvt_f32_bf16<<<4096, 256, 0, stream>>>(x, xb, 1048576);
  cvt_f32_bf16<<<3072, 256, 0, stream>>>(w_qkv, wqkvb, 786432);
  cvt_f32_bf16<<<1024, 256, 0, stream>>>(w_out, woutb, 262144);

  // qkv = x @ w_qkv^T : M=4096, N=3072, K=1024  -> bf16
  gemm_bt<<<dim3(32, 24), 256, 0, stream>>>(xb, wqkvb, nullptr, qkvb, nullptr,
                                            4096, 3072, 1024);
  rope_repack<<<8192, 256, 0, stream>>>(qkvb, Qd, Kd);
  v_transpose<<<2048, 256, 0, stream>>>(qkvb, Vtg);
  attn_fwd<<<dim3(32, 16), 256, 0, stream>>>(Qd, Kd, Vtg, attnb);
  // out = attn @ w_out^T + b : M=4096, N=1024, K=1024 -> f32
  gemm_bt<<<dim3(32, 8), 256, 0, stream>>>(attnb, woutb, out, nullptr, b_out,
                                           4096, 1024, 1024);
}